// Round 7
// baseline (241.889 us; speedup 1.0000x reference)
//
#include <hip/hip_runtime.h>

// MHA: B=4, S=2048, D=1024, H=16, Hd=64, causal. fp32 in/out, bf16 MFMA compute.
// cast -> fused QKV gemm (Q scaled, K row-major, V transposed) -> flash attn
// -> out gemm. GEMMs: 128x128 m97-structure, 16x16x32 MFMA.
// attn (R7): 2-wave blocks, 64 q per wave (2 groups of 32), kv-tile 64, 32 KB LDS,
// 4 blocks/CU. Each K/V LDS fragment read feeds 2 MFMAs (one per q-group) ->
// ds_read count per q*kv halved vs R6 (was 1:1 MFMA:read, LDS-issue bound ~18us/CU).
// P exchanged via v_permlane32_swap (D.hi<->S.lo, HW-verified R6); T5 setprio kept.
// History: 256x256 8-phase GEMM slower twice (76 vs 66); 32x32 GEMM frags slower
// (structural 4-way conflict); permlane D.lo<->S.hi convention WRONG (R5 fail).

typedef float f32x4 __attribute__((ext_vector_type(4)));
typedef float f32x16 __attribute__((ext_vector_type(16)));
typedef short s16x8 __attribute__((ext_vector_type(8)));

#if __has_builtin(__builtin_amdgcn_exp2f)
#define EXP2(x) __builtin_amdgcn_exp2f(x)
#else
#define EXP2(x) exp2f(x)
#endif

// RNE float -> bf16 bits
__device__ __forceinline__ unsigned short f2bf(float f) {
  unsigned int u = __float_as_uint(f);
  u += 0x7fffu + ((u >> 16) & 1u);
  return (unsigned short)(u >> 16);
}

// pack two floats to bf16 pair, round-half-up
__device__ __forceinline__ unsigned int pk2bf(float f0, float f1) {
  return __builtin_amdgcn_perm(__float_as_uint(f1) + 0x8000u,
                               __float_as_uint(f0) + 0x8000u, 0x07060302u);
}

// pack two floats to bf16 pair, TRUNCATING (1 v_perm) — for P only
__device__ __forceinline__ unsigned int pk2bf_t(float f0, float f1) {
  return __builtin_amdgcn_perm(__float_as_uint(f1), __float_as_uint(f0), 0x07060302u);
}

// async global->LDS, 16 bytes per lane (wave-uniform LDS base + lane*16)
__device__ __forceinline__ void gl_lds16(const short* g, short* lds) {
  __builtin_amdgcn_global_load_lds(
      (const __attribute__((address_space(1))) unsigned int*)g,
      (__attribute__((address_space(3))) unsigned int*)lds, 16, 0, 0);
}

// ---------------- fp32 -> bf16 cast: X + all 4 weights, one dispatch ----------------
__global__ __launch_bounds__(256) void cvt_all(const float4* __restrict__ X,
                                               const float4* __restrict__ Wq,
                                               const float4* __restrict__ Wk,
                                               const float4* __restrict__ Wv,
                                               const float4* __restrict__ Wo,
                                               ushort4* __restrict__ xb,
                                               ushort4* __restrict__ wqkv,
                                               ushort4* __restrict__ wob) {
  const int NX = 8192 * 1024 / 4;
  const int NW = 1024 * 1024 / 4;
  const int NT = NX + 4 * NW;
  int i = blockIdx.x * blockDim.x + threadIdx.x;
  int stride = gridDim.x * blockDim.x;
  for (int idx = i; idx < NT; idx += stride) {
    const float4* s;
    ushort4* d;
    int off;
    if (idx < NX) {
      s = X; d = xb; off = idx;
    } else {
      int j = idx - NX;
      int w = j >> 18;
      off = j & (NW - 1);
      switch (w) {
        case 0: s = Wq; d = wqkv; break;
        case 1: s = Wk; d = wqkv + NW; break;
        case 2: s = Wv; d = wqkv + 2 * NW; break;
        default: s = Wo; d = wob; break;
      }
    }
    float4 f = s[off];
    ushort4 r;
    r.x = f2bf(f.x); r.y = f2bf(f.y); r.z = f2bf(f.z); r.w = f2bf(f.w);
    d[off] = r;
  }
}

// ---------------- GEMM: C[M,N] = A[M,K] * B[N,K]^T (both bf16 row-major) ----------------
// MODE 0: fp32 output to Cf.
// MODE 1: QKV mode, N=3072: cols [0,1024) -> q_o (scaled bf16), [1024,2048) -> k_o,
//         [2048,3072) -> vT_o transposed as (b,h,d,s) with packed 8B stores.
template <int MODE>
__global__ __launch_bounds__(256) void gemm_bt(const short* __restrict__ A,
                                               const short* __restrict__ B,
                                               float* __restrict__ Cf,
                                               short* __restrict__ q_o,
                                               short* __restrict__ k_o,
                                               short* __restrict__ vT_o,
                                               int M, int N, int K) {
  const int tid = threadIdx.x;
  const int wave = tid >> 6, lane = tid & 63;
  const int quad = lane >> 4, l15 = lane & 15;
  const int m0 = blockIdx.x * 128, n0 = blockIdx.y * 128;
  const int wm = (wave >> 1) * 64, wn = (wave & 1) * 64;

  __shared__ __align__(16) short As[128 * 64];
  __shared__ __align__(16) short Bs[128 * 64];

  const f32x4 z4 = {0.f, 0.f, 0.f, 0.f};
  f32x4 acc[4][4];
  for (int i = 0; i < 4; ++i)
    for (int j = 0; j < 4; ++j) acc[i][j] = z4;

  for (int k0 = 0; k0 < K; k0 += 64) {
    __syncthreads();
    for (int i = 0; i < 4; ++i) {
      int c = wave * 4 + i;
      int r = c * 8 + (lane >> 3);
      int c8 = (lane & 7) ^ (r & 7);
      gl_lds16(A + (size_t)(m0 + r) * K + k0 + c8 * 8, As + c * 512 + lane * 8);
      gl_lds16(B + (size_t)(n0 + r) * K + k0 + c8 * 8, Bs + c * 512 + lane * 8);
    }
    __syncthreads();
    for (int kk = 0; kk < 64; kk += 32) {
      int c8b = (kk >> 3) + quad;
      s16x8 af[4], bfr[4];
      for (int mt = 0; mt < 4; ++mt) {
        int row = wm + mt * 16 + l15;
        af[mt] = *(const s16x8*)(As + row * 64 + ((c8b ^ (row & 7)) << 3));
      }
      for (int nt = 0; nt < 4; ++nt) {
        int row = wn + nt * 16 + l15;
        bfr[nt] = *(const s16x8*)(Bs + row * 64 + ((c8b ^ (row & 7)) << 3));
      }
      for (int mt = 0; mt < 4; ++mt)
        for (int nt = 0; nt < 4; ++nt)
          acc[mt][nt] = __builtin_amdgcn_mfma_f32_16x16x32_bf16(af[mt], bfr[nt],
                                                                acc[mt][nt], 0, 0, 0);
    }
  }

  if (MODE == 0) {
    for (int mt = 0; mt < 4; ++mt)
      for (int nt = 0; nt < 4; ++nt) {
        int col = n0 + wn + nt * 16 + l15;
        for (int r = 0; r < 4; ++r) {
          int row = m0 + wm + mt * 16 + quad * 4 + r;
          Cf[(size_t)row * N + col] = acc[mt][nt][r];
        }
      }
  } else {
    if (n0 < 1024) {  // Q, fold softmax scale * log2(e)
      const float scale = 0.18033688011112042f;  // 0.125 * log2(e)
      for (int mt = 0; mt < 4; ++mt)
        for (int nt = 0; nt < 4; ++nt) {
          int col = n0 + wn + nt * 16 + l15;
          for (int r = 0; r < 4; ++r) {
            int row = m0 + wm + mt * 16 + quad * 4 + r;
            ((unsigned short*)q_o)[(size_t)row * 1024 + col] = f2bf(acc[mt][nt][r] * scale);
          }
        }
    } else if (n0 < 2048) {  // K
      for (int mt = 0; mt < 4; ++mt)
        for (int nt = 0; nt < 4; ++nt) {
          int col = n0 - 1024 + wn + nt * 16 + l15;
          for (int r = 0; r < 4; ++r) {
            int row = m0 + wm + mt * 16 + quad * 4 + r;
            ((unsigned short*)k_o)[(size_t)row * 1024 + col] = f2bf(acc[mt][nt][r]);
          }
        }
    } else {  // V transposed: vT[((b*16+h)*64+d)*2048 + s], 4 consecutive s per lane
      for (int mt = 0; mt < 4; ++mt)
        for (int nt = 0; nt < 4; ++nt) {
          int col = n0 - 2048 + wn + nt * 16 + l15;
          int h = col >> 6, d = col & 63;
          int row0 = m0 + wm + mt * 16 + quad * 4;
          int b = row0 >> 11, s = row0 & 2047;
          uint2 pk;
          pk.x = pk2bf(acc[mt][nt][0], acc[mt][nt][1]);
          pk.y = pk2bf(acc[mt][nt][2], acc[mt][nt][3]);
          *(uint2*)((unsigned short*)vT_o + (((size_t)b * 16 + h) * 64 + d) * 2048 + s) = pk;
        }
    }
  }
}

// ---------------- flash attention: 2 waves x 64 q, kv-tile 64, shared frag reads ------
// grid (64 bh, 16 y): qt = 15 - y. Block = 128 threads (2 waves), each wave owns
// 64 q rows = two 32-q groups (A: +0, B: +32). Per kv-tile iteration each K/V
// fragment read feeds TWO MFMAs (groups A,B) -> 16 ds_read_b128 : 32 MFMA.
// Wave w's last active tile is 2qt+w; both its groups hit the diagonal there:
//   A: m=0 mask rloc>l31, m=1 fully masked;  B: m=0 clear, m=1 mask rloc>l31.
// Wave 0 is barrier-only on the block's final tile (t = 2qt+1).
// K/V^T double-buffered (32 KB total -> 4 blocks/CU); DMA for t+1 issued right
// after the per-iter barrier. T5 setprio on MFMA clusters; P exchange via
// v_permlane32_swap (D.hi<->S.lo, HW-verified R6).
__global__ __launch_bounds__(128, 2) void attn_kernel(const short* __restrict__ qb,
                                                      const short* __restrict__ kb,
                                                      const short* __restrict__ vT,
                                                      short* __restrict__ ob) {
  const int bh = blockIdx.x;
  const int qt = 15 - (int)blockIdx.y;
  const int tid = threadIdx.x;
  const int wave = tid >> 6, lane = tid & 63;
  const int l31 = lane & 31, h = lane >> 5;
  const int q0 = qt * 128;
  const size_t rowbase = (size_t)(bh >> 4) * 2048;
  const int hoff = (bh & 15) * 64;

  __shared__ __align__(16) short Ks[2][4096];   // 64 kv x 64 d, swizzled (8 KB each)
  __shared__ __align__(16) short VTs[2][4096];  // 64 d x 64 kv, swizzled (8 KB each)

  // staging: 8 chunks of 512 shorts per tile; wave stages chunks wave*4 .. +3
  const int kc = wave * 4;
  const int kr = kc * 8 + (lane >> 3);            // K row in [0,64), 8 rows per chunk
  const short* ksrc = kb + (rowbase + kr) * 1024 + hoff + (((lane & 7) ^ (kr & 7)) << 3);
  const int vg = lane & 7;                        // kv chunk-of-8 within 64
  const short* vsrc_i[4];
#pragma unroll
  for (int i = 0; i < 4; ++i) {
    int d = (kc + i) * 8 + (lane >> 3);           // V^T d-row (8 rows per chunk)
    vsrc_i[i] = vT + ((size_t)bh * 64 + d) * 2048 + ((vg ^ (d & 7)) << 3);
  }

  // Q B-frags, two groups: q = q0 + wave*64 + G*32 + l31; d = ks*16 + h*8 + j
  s16x8 qfA[4], qfB[4];
  {
    const short* qrowA = qb + (rowbase + q0 + wave * 64 + l31) * 1024 + hoff + h * 8;
    const short* qrowB = qrowA + 32 * 1024;
#pragma unroll
    for (int k = 0; k < 4; ++k) {
      qfA[k] = *(const s16x8*)(qrowA + k * 16);
      qfB[k] = *(const s16x8*)(qrowB + k * 16);
    }
  }

  // prologue: stage tile 0 into buffer 0
#pragma unroll
  for (int i = 0; i < 4; ++i)
    gl_lds16(ksrc + i * 8 * 1024, Ks[0] + (kc + i) * 512 + lane * 8);
#pragma unroll
  for (int i = 0; i < 4; ++i)
    gl_lds16(vsrc_i[i], VTs[0] + (kc + i) * 512 + lane * 8);

  f32x16 oaccA[2], oaccB[2];  // O^T per group: col=q=l31, row_d=(e&3)+8*(e>>2)+4h+32dt
#pragma unroll
  for (int dt = 0; dt < 2; ++dt)
#pragma unroll
    for (int e = 0; e < 16; ++e) { oaccA[dt][e] = 0.f; oaccB[dt][e] = 0.f; }
  float laccA = 0.f, laccB = 0.f;
  const int kswz = l31 & 7;
  const int TT = 2 * qt + 1;        // block's last kv-64 tile
  const int myT = 2 * qt + wave;    // this wave's last active tile (diagonal there)

  for (int t = 0; t <= TT; ++t) {
    __syncthreads();  // drains DMA(t) (issued last iter); LDS reads of old buf done
    const int cur = t & 1;

    if (t < TT) {  // stage t+1 into alternate buffers
      const int nxt = cur ^ 1;
      const short* ks = ksrc + (size_t)(t + 1) * 64 * 1024;
#pragma unroll
      for (int i = 0; i < 4; ++i)
        gl_lds16(ks + i * 8 * 1024, Ks[nxt] + (kc + i) * 512 + lane * 8);
#pragma unroll
      for (int i = 0; i < 4; ++i)
        gl_lds16(vsrc_i[i] + (t + 1) * 64, VTs[nxt] + (kc + i) * 512 + lane * 8);
    }

    if (t > myT) continue;  // wave 0 on final tile: barrier/staging only

    const short* Kc = Ks[cur];
    const short* Vc = VTs[cur];

    // S^T = K * Q^T for both groups; K frags shared. 2 m-tiles of 32 kv.
    // C-layout: col=q=l31, row_kv = (e&3)+8*(e>>2)+4h (+32m).
    unsigned int ppA[2][8], ppB[2][8];
    float sumA = 0.f, sumB = 0.f;
    {
      f32x16 sA0, sA1, sB0, sB1;
#pragma unroll
      for (int e = 0; e < 16; ++e) { sA0[e] = 0.f; sA1[e] = 0.f; sB0[e] = 0.f; sB1[e] = 0.f; }
      __builtin_amdgcn_s_setprio(1);
#pragma unroll
      for (int ks = 0; ks < 4; ++ks) {
        int pos = ((ks << 1) + h) ^ kswz;
        s16x8 kf0 = *(const s16x8*)(Kc + (l31) * 64 + (pos << 3));
        s16x8 kf1 = *(const s16x8*)(Kc + (32 + l31) * 64 + (pos << 3));
        sA0 = __builtin_amdgcn_mfma_f32_32x32x16_bf16(kf0, qfA[ks], sA0, 0, 0, 0);
        sB0 = __builtin_amdgcn_mfma_f32_32x32x16_bf16(kf0, qfB[ks], sB0, 0, 0, 0);
        sA1 = __builtin_amdgcn_mfma_f32_32x32x16_bf16(kf1, qfA[ks], sA1, 0, 0, 0);
        sB1 = __builtin_amdgcn_mfma_f32_32x32x16_bf16(kf1, qfB[ks], sB1, 0, 0, 0);
      }
      __builtin_amdgcn_s_setprio(0);
      if (t == myT) {  // diagonal tile for BOTH groups of this wave
#pragma unroll
        for (int e = 0; e < 16; ++e) {
          int rloc = (e & 3) + 8 * (e >> 2) + 4 * h;
          if (rloc > l31) { sA0[e] = -1e30f; sB1[e] = -1e30f; }
          sA1[e] = -1e30f;  // kv rows 32..63 all above group A's q
        }
      }
#pragma unroll
      for (int rg = 0; rg < 8; ++rg) {
        float a0 = EXP2(sA0[2 * rg]), a1 = EXP2(sA0[2 * rg + 1]);
        float a2 = EXP2(sA1[2 * rg]), a3 = EXP2(sA1[2 * rg + 1]);
        float b0 = EXP2(sB0[2 * rg]), b1 = EXP2(sB0[2 * rg + 1]);
        float b2 = EXP2(sB1[2 * rg]), b3 = EXP2(sB1[2 * rg + 1]);
        sumA += (a0 + a1) + (a2 + a3);
        sumB += (b0 + b1) + (b2 + b3);
        ppA[0][rg] = pk2bf_t(a0, a1);
        ppA[1][rg] = pk2bf_t(a2, a3);
        ppB[0][rg] = pk2bf_t(b0, b1);
        ppB[1][rg] = pk2bf_t(b2, b3);
      }
    }
    laccA += sumA; laccB += sumB;

    // O^T += V^T * P^T for both groups; V frags shared. B-frag kv = s*16 + h*8 + j.
#pragma unroll
    for (int s = 0; s < 4; ++s) {
      int m = s >> 1, base = (s & 1) * 4;
      unsigned int aAx = ppA[m][base + 0], aAy = ppA[m][base + 1];
      unsigned int bAx = ppA[m][base + 2], bAy = ppA[m][base + 3];
      asm("v_permlane32_swap_b32 %0, %1" : "+v"(aAx), "+v"(bAx));
      asm("v_permlane32_swap_b32 %0, %1" : "+v"(aAy), "+v"(bAy));
      unsigned int aBx = ppB[m][base + 0], aBy = ppB[m][base + 1];
      unsigned int bBx = ppB[m][base + 2], bBy = ppB[m][base + 3];
      asm("v_permlane32_swap_b32 %0, %1" : "+v"(aBx), "+v"(bBx));
      asm("v_permlane32_swap_b32 %0, %1" : "+v"(aBy), "+v"(bBy));
      union { s16x8 v; unsigned int u[4]; } pfA, pfB;
      pfA.u[0] = aAx; pfA.u[1] = aAy; pfA.u[2] = bAx; pfA.u[3] = bAy;
      pfB.u[0] = aBx; pfB.u[1] = aBy; pfB.u[2] = bBx; pfB.u[3] = bBy;
      __builtin_amdgcn_s_setprio(1);
#pragma unroll
      for (int dt = 0; dt < 2; ++dt) {
        int d = dt * 32 + l31;
        s16x8 vf = *(const s16x8*)(Vc + d * 64 + ((((s << 1) + h) ^ (d & 7)) << 3));
        oaccA[dt] = __builtin_amdgcn_mfma_f32_32x32x16_bf16(vf, pfA.v, oaccA[dt], 0, 0, 0);
        oaccB[dt] = __builtin_amdgcn_mfma_f32_32x32x16_bf16(vf, pfB.v, oaccB[dt], 0, 0, 0);
      }
      __builtin_amdgcn_s_setprio(0);
    }
  }

  // epilogue: l across the two half-lanes, normalize, store O rows (8B stores)
  laccA += __shfl_xor(laccA, 32);
  laccB += __shfl_xor(laccB, 32);
  float invA = 1.0f / laccA, invB = 1.0f / laccB;
  size_t rowA = rowbase + q0 + wave * 64 + l31;
  unsigned short* orowA = (unsigned short*)ob + rowA * 1024 + hoff;
  unsigned short* orowB = orowA + 32 * 1024;
#pragma unroll
  for (int dt = 0; dt < 2; ++dt)
#pragma unroll
    for (int rg = 0; rg < 4; ++rg) {
      int d = dt * 32 + rg * 8 + 4 * h;
      uint2 pkA, pkB;
      pkA.x = pk2bf(oaccA[dt][rg * 4 + 0] * invA, oaccA[dt][rg * 4 + 1] * invA);
      pkA.y = pk2bf(oaccA[dt][rg * 4 + 2] * invA, oaccA[dt][rg * 4 + 3] * invA);
      pkB.x = pk2bf(oaccB[dt][rg * 4 + 0] * invB, oaccB[dt][rg * 4 + 1] * invB);
      pkB.y = pk2bf(oaccB[dt][rg * 4 + 2] * invB, oaccB[dt][rg * 4 + 3] * invB);
      *(uint2*)(orowA + d) = pkA;
      *(uint2*)(orowB + d) = pkB;
    }
}

extern "C" void kernel_launch(void* const* d_in, const int* in_sizes, int n_in,
                              void* d_out, int out_size, void* d_ws, size_t ws_size,
                              hipStream_t stream) {
  const float* X  = (const float*)d_in[0];
  const float* Wq = (const float*)d_in[1];
  const float* Wk = (const float*)d_in[2];
  const float* Wv = (const float*)d_in[3];
  const float* Wo = (const float*)d_in[4];

  // workspace (bf16 shorts), 72 MB total; ob aliases xb (dead after QKV gemm)
  short* xb   = (short*)d_ws;                    // 8192x1024 (16 MB)
  short* wqkv = xb + (size_t)8192 * 1024;        // 3072x1024 ( 6 MB)
  short* wob  = wqkv + (size_t)3072 * 1024;      // 1024x1024 ( 2 MB)
  short* qb   = wob + (size_t)1024 * 1024;       // 8192x1024 (16 MB)
  short* kb   = qb + (size_t)8192 * 1024;        // 8192x1024 (16 MB)
  short* vT   = kb + (size_t)8192 * 1024;        // (4,16,64,2048) (16 MB)
  short* ob   = xb;

  const int MB = 8192;

  cvt_all<<<3072, 256, 0, stream>>>((const float4*)X, (const float4*)Wq, (const float4*)Wk,
                                    (const float4*)Wv, (const float4*)Wo, (ushort4*)xb,
                                    (ushort4*)wqkv, (ushort4*)wob);

  // fused QKV projection -> qb (scaled), kb, vT
  gemm_bt<1><<<dim3(64, 24), 256, 0, stream>>>(xb, wqkv, nullptr, qb, kb, vT, MB, 3072, 1024);

  // flash attention -> ob (bf16)
  attn_kernel<<<dim3(64, 16), 128, 0, stream>>>(qb, kb, vT, ob);

  // output projection -> fp32 d_out
  gemm_bt<0><<<dim3(64, 8), 256, 0, stream>>>(ob, wob, (float*)d_out, nullptr, nullptr,
                                              nullptr, MB, 1024, 1024);
}

// Round 8
// 241.869 us; speedup vs baseline: 1.0001x; 1.0001x over previous
//
#include <hip/hip_runtime.h>

// MHA: B=4, S=2048, D=1024, H=16, Hd=64, causal. fp32 in/out, bf16 MFMA compute.
// cast -> fused QKV gemm (Q scaled, K row-major, V transposed) -> flash attn
// -> out gemm. GEMMs: 128x128 m97-structure, 16x16x32 MFMA.
// attn: 2-wave blocks, 64 q per wave (2 groups of 32), kv-tile 64, 32 KB LDS,
// 4 blocks/CU. Each K/V LDS fragment read feeds 2 MFMAs (one per q-group) ->
// ds_read count per q*kv halved vs the 4-wave/128-kv version.
// P exchanged via v_permlane32_swap (D.hi<->S.lo, HW-verified R6); T5 setprio kept.
// NOTE R8 = R7 resubmitted verbatim: R7 ran on a freshly-acquired (different)
// chip — identical gemm_bt code measured +9% (66.5->72.5 us), so the attn delta
// was confounded. gemm_bt<1> dur is the condition anchor for this round.
// History: 256x256 8-phase GEMM slower twice (76 vs 66); 32x32 GEMM frags slower
// (structural 4-way conflict); permlane D.lo<->S.hi convention WRONG (R5 fail).

typedef float f32x4 __attribute__((ext_vector_type(4)));
typedef float f32x16 __attribute__((ext_vector_type(16)));
typedef short s16x8 __attribute__((ext_vector_type(8)));

#if __has_builtin(__builtin_amdgcn_exp2f)
#define EXP2(x) __builtin_amdgcn_exp2f(x)
#else
#define EXP2(x) exp2f(x)
#endif

// RNE float -> bf16 bits
__device__ __forceinline__ unsigned short f2bf(float f) {
  unsigned int u = __float_as_uint(f);
  u += 0x7fffu + ((u >> 16) & 1u);
  return (unsigned short)(u >> 16);
}

// pack two floats to bf16 pair, round-half-up
__device__ __forceinline__ unsigned int pk2bf(float f0, float f1) {
  return __builtin_amdgcn_perm(__float_as_uint(f1) + 0x8000u,
                               __float_as_uint(f0) + 0x8000u, 0x07060302u);
}

// pack two floats to bf16 pair, TRUNCATING (1 v_perm) — for P only
__device__ __forceinline__ unsigned int pk2bf_t(float f0, float f1) {
  return __builtin_amdgcn_perm(__float_as_uint(f1), __float_as_uint(f0), 0x07060302u);
}

// async global->LDS, 16 bytes per lane (wave-uniform LDS base + lane*16)
__device__ __forceinline__ void gl_lds16(const short* g, short* lds) {
  __builtin_amdgcn_global_load_lds(
      (const __attribute__((address_space(1))) unsigned int*)g,
      (__attribute__((address_space(3))) unsigned int*)lds, 16, 0, 0);
}

// ---------------- fp32 -> bf16 cast: X + all 4 weights, one dispatch ----------------
__global__ __launch_bounds__(256) void cvt_all(const float4* __restrict__ X,
                                               const float4* __restrict__ Wq,
                                               const float4* __restrict__ Wk,
                                               const float4* __restrict__ Wv,
                                               const float4* __restrict__ Wo,
                                               ushort4* __restrict__ xb,
                                               ushort4* __restrict__ wqkv,
                                               ushort4* __restrict__ wob) {
  const int NX = 8192 * 1024 / 4;
  const int NW = 1024 * 1024 / 4;
  const int NT = NX + 4 * NW;
  int i = blockIdx.x * blockDim.x + threadIdx.x;
  int stride = gridDim.x * blockDim.x;
  for (int idx = i; idx < NT; idx += stride) {
    const float4* s;
    ushort4* d;
    int off;
    if (idx < NX) {
      s = X; d = xb; off = idx;
    } else {
      int j = idx - NX;
      int w = j >> 18;
      off = j & (NW - 1);
      switch (w) {
        case 0: s = Wq; d = wqkv; break;
        case 1: s = Wk; d = wqkv + NW; break;
        case 2: s = Wv; d = wqkv + 2 * NW; break;
        default: s = Wo; d = wob; break;
      }
    }
    float4 f = s[off];
    ushort4 r;
    r.x = f2bf(f.x); r.y = f2bf(f.y); r.z = f2bf(f.z); r.w = f2bf(f.w);
    d[off] = r;
  }
}

// ---------------- GEMM: C[M,N] = A[M,K] * B[N,K]^T (both bf16 row-major) ----------------
// MODE 0: fp32 output to Cf.
// MODE 1: QKV mode, N=3072: cols [0,1024) -> q_o (scaled bf16), [1024,2048) -> k_o,
//         [2048,3072) -> vT_o transposed as (b,h,d,s) with packed 8B stores.
template <int MODE>
__global__ __launch_bounds__(256) void gemm_bt(const short* __restrict__ A,
                                               const short* __restrict__ B,
                                               float* __restrict__ Cf,
                                               short* __restrict__ q_o,
                                               short* __restrict__ k_o,
                                               short* __restrict__ vT_o,
                                               int M, int N, int K) {
  const int tid = threadIdx.x;
  const int wave = tid >> 6, lane = tid & 63;
  const int quad = lane >> 4, l15 = lane & 15;
  const int m0 = blockIdx.x * 128, n0 = blockIdx.y * 128;
  const int wm = (wave >> 1) * 64, wn = (wave & 1) * 64;

  __shared__ __align__(16) short As[128 * 64];
  __shared__ __align__(16) short Bs[128 * 64];

  const f32x4 z4 = {0.f, 0.f, 0.f, 0.f};
  f32x4 acc[4][4];
  for (int i = 0; i < 4; ++i)
    for (int j = 0; j < 4; ++j) acc[i][j] = z4;

  for (int k0 = 0; k0 < K; k0 += 64) {
    __syncthreads();
    for (int i = 0; i < 4; ++i) {
      int c = wave * 4 + i;
      int r = c * 8 + (lane >> 3);
      int c8 = (lane & 7) ^ (r & 7);
      gl_lds16(A + (size_t)(m0 + r) * K + k0 + c8 * 8, As + c * 512 + lane * 8);
      gl_lds16(B + (size_t)(n0 + r) * K + k0 + c8 * 8, Bs + c * 512 + lane * 8);
    }
    __syncthreads();
    for (int kk = 0; kk < 64; kk += 32) {
      int c8b = (kk >> 3) + quad;
      s16x8 af[4], bfr[4];
      for (int mt = 0; mt < 4; ++mt) {
        int row = wm + mt * 16 + l15;
        af[mt] = *(const s16x8*)(As + row * 64 + ((c8b ^ (row & 7)) << 3));
      }
      for (int nt = 0; nt < 4; ++nt) {
        int row = wn + nt * 16 + l15;
        bfr[nt] = *(const s16x8*)(Bs + row * 64 + ((c8b ^ (row & 7)) << 3));
      }
      for (int mt = 0; mt < 4; ++mt)
        for (int nt = 0; nt < 4; ++nt)
          acc[mt][nt] = __builtin_amdgcn_mfma_f32_16x16x32_bf16(af[mt], bfr[nt],
                                                                acc[mt][nt], 0, 0, 0);
    }
  }

  if (MODE == 0) {
    for (int mt = 0; mt < 4; ++mt)
      for (int nt = 0; nt < 4; ++nt) {
        int col = n0 + wn + nt * 16 + l15;
        for (int r = 0; r < 4; ++r) {
          int row = m0 + wm + mt * 16 + quad * 4 + r;
          Cf[(size_t)row * N + col] = acc[mt][nt][r];
        }
      }
  } else {
    if (n0 < 1024) {  // Q, fold softmax scale * log2(e)
      const float scale = 0.18033688011112042f;  // 0.125 * log2(e)
      for (int mt = 0; mt < 4; ++mt)
        for (int nt = 0; nt < 4; ++nt) {
          int col = n0 + wn + nt * 16 + l15;
          for (int r = 0; r < 4; ++r) {
            int row = m0 + wm + mt * 16 + quad * 4 + r;
            ((unsigned short*)q_o)[(size_t)row * 1024 + col] = f2bf(acc[mt][nt][r] * scale);
          }
        }
    } else if (n0 < 2048) {  // K
      for (int mt = 0; mt < 4; ++mt)
        for (int nt = 0; nt < 4; ++nt) {
          int col = n0 - 1024 + wn + nt * 16 + l15;
          for (int r = 0; r < 4; ++r) {
            int row = m0 + wm + mt * 16 + quad * 4 + r;
            ((unsigned short*)k_o)[(size_t)row * 1024 + col] = f2bf(acc[mt][nt][r]);
          }
        }
    } else {  // V transposed: vT[((b*16+h)*64+d)*2048 + s], 4 consecutive s per lane
      for (int mt = 0; mt < 4; ++mt)
        for (int nt = 0; nt < 4; ++nt) {
          int col = n0 - 2048 + wn + nt * 16 + l15;
          int h = col >> 6, d = col & 63;
          int row0 = m0 + wm + mt * 16 + quad * 4;
          int b = row0 >> 11, s = row0 & 2047;
          uint2 pk;
          pk.x = pk2bf(acc[mt][nt][0], acc[mt][nt][1]);
          pk.y = pk2bf(acc[mt][nt][2], acc[mt][nt][3]);
          *(uint2*)((unsigned short*)vT_o + (((size_t)b * 16 + h) * 64 + d) * 2048 + s) = pk;
        }
    }
  }
}

// ---------------- flash attention: 2 waves x 64 q, kv-tile 64, shared frag reads ------
// grid (64 bh, 16 y): qt = 15 - y. Block = 128 threads (2 waves), each wave owns
// 64 q rows = two 32-q groups (A: +0, B: +32). Per kv-tile iteration each K/V
// fragment read feeds TWO MFMAs (groups A,B) -> 16 ds_read_b128 : 32 MFMA.
// Wave w's last active tile is 2qt+w; both its groups hit the diagonal there:
//   A: m=0 mask rloc>l31, m=1 fully masked;  B: m=0 clear, m=1 mask rloc>l31.
// Wave 0 is barrier-only on the block's final tile (t = 2qt+1).
// K/V^T double-buffered (32 KB total -> 4 blocks/CU); DMA for t+1 issued right
// after the per-iter barrier. T5 setprio on MFMA clusters; P exchange via
// v_permlane32_swap (D.hi<->S.lo, HW-verified R6).
__global__ __launch_bounds__(128, 2) void attn_kernel(const short* __restrict__ qb,
                                                      const short* __restrict__ kb,
                                                      const short* __restrict__ vT,
                                                      short* __restrict__ ob) {
  const int bh = blockIdx.x;
  const int qt = 15 - (int)blockIdx.y;
  const int tid = threadIdx.x;
  const int wave = tid >> 6, lane = tid & 63;
  const int l31 = lane & 31, h = lane >> 5;
  const int q0 = qt * 128;
  const size_t rowbase = (size_t)(bh >> 4) * 2048;
  const int hoff = (bh & 15) * 64;

  __shared__ __align__(16) short Ks[2][4096];   // 64 kv x 64 d, swizzled (8 KB each)
  __shared__ __align__(16) short VTs[2][4096];  // 64 d x 64 kv, swizzled (8 KB each)

  // staging: 8 chunks of 512 shorts per tile; wave stages chunks wave*4 .. +3
  const int kc = wave * 4;
  const int kr = kc * 8 + (lane >> 3);            // K row in [0,64), 8 rows per chunk
  const short* ksrc = kb + (rowbase + kr) * 1024 + hoff + (((lane & 7) ^ (kr & 7)) << 3);
  const int vg = lane & 7;                        // kv chunk-of-8 within 64
  const short* vsrc_i[4];
#pragma unroll
  for (int i = 0; i < 4; ++i) {
    int d = (kc + i) * 8 + (lane >> 3);           // V^T d-row (8 rows per chunk)
    vsrc_i[i] = vT + ((size_t)bh * 64 + d) * 2048 + ((vg ^ (d & 7)) << 3);
  }

  // Q B-frags, two groups: q = q0 + wave*64 + G*32 + l31; d = ks*16 + h*8 + j
  s16x8 qfA[4], qfB[4];
  {
    const short* qrowA = qb + (rowbase + q0 + wave * 64 + l31) * 1024 + hoff + h * 8;
    const short* qrowB = qrowA + 32 * 1024;
#pragma unroll
    for (int k = 0; k < 4; ++k) {
      qfA[k] = *(const s16x8*)(qrowA + k * 16);
      qfB[k] = *(const s16x8*)(qrowB + k * 16);
    }
  }

  // prologue: stage tile 0 into buffer 0
#pragma unroll
  for (int i = 0; i < 4; ++i)
    gl_lds16(ksrc + i * 8 * 1024, Ks[0] + (kc + i) * 512 + lane * 8);
#pragma unroll
  for (int i = 0; i < 4; ++i)
    gl_lds16(vsrc_i[i], VTs[0] + (kc + i) * 512 + lane * 8);

  f32x16 oaccA[2], oaccB[2];  // O^T per group: col=q=l31, row_d=(e&3)+8*(e>>2)+4h+32dt
#pragma unroll
  for (int dt = 0; dt < 2; ++dt)
#pragma unroll
    for (int e = 0; e < 16; ++e) { oaccA[dt][e] = 0.f; oaccB[dt][e] = 0.f; }
  float laccA = 0.f, laccB = 0.f;
  const int kswz = l31 & 7;
  const int TT = 2 * qt + 1;        // block's last kv-64 tile
  const int myT = 2 * qt + wave;    // this wave's last active tile (diagonal there)

  for (int t = 0; t <= TT; ++t) {
    __syncthreads();  // drains DMA(t) (issued last iter); LDS reads of old buf done
    const int cur = t & 1;

    if (t < TT) {  // stage t+1 into alternate buffers
      const int nxt = cur ^ 1;
      const short* ks = ksrc + (size_t)(t + 1) * 64 * 1024;
#pragma unroll
      for (int i = 0; i < 4; ++i)
        gl_lds16(ks + i * 8 * 1024, Ks[nxt] + (kc + i) * 512 + lane * 8);
#pragma unroll
      for (int i = 0; i < 4; ++i)
        gl_lds16(vsrc_i[i] + (t + 1) * 64, VTs[nxt] + (kc + i) * 512 + lane * 8);
    }

    if (t > myT) continue;  // wave 0 on final tile: barrier/staging only

    const short* Kc = Ks[cur];
    const short* Vc = VTs[cur];

    // S^T = K * Q^T for both groups; K frags shared. 2 m-tiles of 32 kv.
    // C-layout: col=q=l31, row_kv = (e&3)+8*(e>>2)+4h (+32m).
    unsigned int ppA[2][8], ppB[2][8];
    float sumA = 0.f, sumB = 0.f;
    {
      f32x16 sA0, sA1, sB0, sB1;
#pragma unroll
      for (int e = 0; e < 16; ++e) { sA0[e] = 0.f; sA1[e] = 0.f; sB0[e] = 0.f; sB1[e] = 0.f; }
      __builtin_amdgcn_s_setprio(1);
#pragma unroll
      for (int ks = 0; ks < 4; ++ks) {
        int pos = ((ks << 1) + h) ^ kswz;
        s16x8 kf0 = *(const s16x8*)(Kc + (l31) * 64 + (pos << 3));
        s16x8 kf1 = *(const s16x8*)(Kc + (32 + l31) * 64 + (pos << 3));
        sA0 = __builtin_amdgcn_mfma_f32_32x32x16_bf16(kf0, qfA[ks], sA0, 0, 0, 0);
        sB0 = __builtin_amdgcn_mfma_f32_32x32x16_bf16(kf0, qfB[ks], sB0, 0, 0, 0);
        sA1 = __builtin_amdgcn_mfma_f32_32x32x16_bf16(kf1, qfA[ks], sA1, 0, 0, 0);
        sB1 = __builtin_amdgcn_mfma_f32_32x32x16_bf16(kf1, qfB[ks], sB1, 0, 0, 0);
      }
      __builtin_amdgcn_s_setprio(0);
      if (t == myT) {  // diagonal tile for BOTH groups of this wave
#pragma unroll
        for (int e = 0; e < 16; ++e) {
          int rloc = (e & 3) + 8 * (e >> 2) + 4 * h;
          if (rloc > l31) { sA0[e] = -1e30f; sB1[e] = -1e30f; }
          sA1[e] = -1e30f;  // kv rows 32..63 all above group A's q
        }
      }
#pragma unroll
      for (int rg = 0; rg < 8; ++rg) {
        float a0 = EXP2(sA0[2 * rg]), a1 = EXP2(sA0[2 * rg + 1]);
        float a2 = EXP2(sA1[2 * rg]), a3 = EXP2(sA1[2 * rg + 1]);
        float b0 = EXP2(sB0[2 * rg]), b1 = EXP2(sB0[2 * rg + 1]);
        float b2 = EXP2(sB1[2 * rg]), b3 = EXP2(sB1[2 * rg + 1]);
        sumA += (a0 + a1) + (a2 + a3);
        sumB += (b0 + b1) + (b2 + b3);
        ppA[0][rg] = pk2bf_t(a0, a1);
        ppA[1][rg] = pk2bf_t(a2, a3);
        ppB[0][rg] = pk2bf_t(b0, b1);
        ppB[1][rg] = pk2bf_t(b2, b3);
      }
    }
    laccA += sumA; laccB += sumB;

    // O^T += V^T * P^T for both groups; V frags shared. B-frag kv = s*16 + h*8 + j.
#pragma unroll
    for (int s = 0; s < 4; ++s) {
      int m = s >> 1, base = (s & 1) * 4;
      unsigned int aAx = ppA[m][base + 0], aAy = ppA[m][base + 1];
      unsigned int bAx = ppA[m][base + 2], bAy = ppA[m][base + 3];
      asm("v_permlane32_swap_b32 %0, %1" : "+v"(aAx), "+v"(bAx));
      asm("v_permlane32_swap_b32 %0, %1" : "+v"(aAy), "+v"(bAy));
      unsigned int aBx = ppB[m][base + 0], aBy = ppB[m][base + 1];
      unsigned int bBx = ppB[m][base + 2], bBy = ppB[m][base + 3];
      asm("v_permlane32_swap_b32 %0, %1" : "+v"(aBx), "+v"(bBx));
      asm("v_permlane32_swap_b32 %0, %1" : "+v"(aBy), "+v"(bBy));
      union { s16x8 v; unsigned int u[4]; } pfA, pfB;
      pfA.u[0] = aAx; pfA.u[1] = aAy; pfA.u[2] = bAx; pfA.u[3] = bAy;
      pfB.u[0] = aBx; pfB.u[1] = aBy; pfB.u[2] = bBx; pfB.u[3] = bBy;
      __builtin_amdgcn_s_setprio(1);
#pragma unroll
      for (int dt = 0; dt < 2; ++dt) {
        int d = dt * 32 + l31;
        s16x8 vf = *(const s16x8*)(Vc + d * 64 + ((((s << 1) + h) ^ (d & 7)) << 3));
        oaccA[dt] = __builtin_amdgcn_mfma_f32_32x32x16_bf16(vf, pfA.v, oaccA[dt], 0, 0, 0);
        oaccB[dt] = __builtin_amdgcn_mfma_f32_32x32x16_bf16(vf, pfB.v, oaccB[dt], 0, 0, 0);
      }
      __builtin_amdgcn_s_setprio(0);
    }
  }

  // epilogue: l across the two half-lanes, normalize, store O rows (8B stores)
  laccA += __shfl_xor(laccA, 32);
  laccB += __shfl_xor(laccB, 32);
  float invA = 1.0f / laccA, invB = 1.0f / laccB;
  size_t rowA = rowbase + q0 + wave * 64 + l31;
  unsigned short* orowA = (unsigned short*)ob + rowA * 1024 + hoff;
  unsigned short* orowB = orowA + 32 * 1024;
#pragma unroll
  for (int dt = 0; dt < 2; ++dt)
#pragma unroll
    for (int rg = 0; rg < 4; ++rg) {
      int d = dt * 32 + rg * 8 + 4 * h;
      uint2 pkA, pkB;
      pkA.x = pk2bf(oaccA[dt][rg * 4 + 0] * invA, oaccA[dt][rg * 4 + 1] * invA);
      pkA.y = pk2bf(oaccA[dt][rg * 4 + 2] * invA, oaccA[dt][rg * 4 + 3] * invA);
      pkB.x = pk2bf(oaccB[dt][rg * 4 + 0] * invB, oaccB[dt][rg * 4 + 1] * invB);
      pkB.y = pk2bf(oaccB[dt][rg * 4 + 2] * invB, oaccB[dt][rg * 4 + 3] * invB);
      *(uint2*)(orowA + d) = pkA;
      *(uint2*)(orowB + d) = pkB;
    }
}

extern "C" void kernel_launch(void* const* d_in, const int* in_sizes, int n_in,
                              void* d_out, int out_size, void* d_ws, size_t ws_size,
                              hipStream_t stream) {
  const float* X  = (const float*)d_in[0];
  const float* Wq = (const float*)d_in[1];
  const float* Wk = (const float*)d_in[2];
  const float* Wv = (const float*)d_in[3];
  const float* Wo = (const float*)d_in[4];

  // workspace (bf16 shorts), 72 MB total; ob aliases xb (dead after QKV gemm)
  short* xb   = (short*)d_ws;                    // 8192x1024 (16 MB)
  short* wqkv = xb + (size_t)8192 * 1024;        // 3072x1024 ( 6 MB)
  short* wob  = wqkv + (size_t)3072 * 1024;      // 1024x1024 ( 2 MB)
  short* qb   = wob + (size_t)1024 * 1024;       // 8192x1024 (16 MB)
  short* kb   = qb + (size_t)8192 * 1024;        // 8192x1024 (16 MB)
  short* vT   = kb + (size_t)8192 * 1024;        // (4,16,64,2048) (16 MB)
  short* ob   = xb;

  const int MB = 8192;

  cvt_all<<<3072, 256, 0, stream>>>((const float4*)X, (const float4*)Wq, (const float4*)Wk,
                                    (const float4*)Wv, (const float4*)Wo, (ushort4*)xb,
                                    (ushort4*)wqkv, (ushort4*)wob);

  // fused QKV projection -> qb (scaled), kb, vT
  gemm_bt<1><<<dim3(64, 24), 256, 0, stream>>>(xb, wqkv, nullptr, qb, kb, vT, MB, 3072, 1024);

  // flash attention -> ob (bf16)
  attn_kernel<<<dim3(64, 16), 128, 0, stream>>>(qb, kb, vT, ob);

  // output projection -> fp32 d_out
  gemm_bt<0><<<dim3(64, 8), 256, 0, stream>>>(ob, wob, (float*)d_out, nullptr, nullptr,
                                              nullptr, MB, 1024, 1024);
}

// Round 9
// 235.703 us; speedup vs baseline: 1.0262x; 1.0262x over previous
//
#include <hip/hip_runtime.h>

// MHA: B=4, S=2048, D=1024, H=16, Hd=64, causal. fp32 in/out, bf16 MFMA compute.
// cast -> fused QKV gemm (Q scaled, K row-major, V transposed) -> flash attn
// (32x32x16 MFMA, K+V^T double-buffered LDS w/ 1 barrier/iter, P exchanged via
// v_permlane32_swap in registers; T5 setprio on MFMA clusters) -> out gemm.
// GEMMs: 128x128 m97-structure, 16x16x32 MFMA.
// == This is the R6 configuration (best verified: 228.2 us) ==
// History (all measured WORSE, reverted): 256x256 8-phase QKV 76 vs 66 (x2);
// 32x32 GEMM frags 75.5 (structural 4-way LDS conflict, h-only column group);
// permlane D.lo<->S.hi convention (R5 correctness fail -> D.hi<->S.lo is correct);
// 2-wave/64q/64kv attn 66 vs ~60 (R7/R8: occupancy 13%, TLP loss > read savings).

typedef float f32x4 __attribute__((ext_vector_type(4)));
typedef float f32x16 __attribute__((ext_vector_type(16)));
typedef short s16x8 __attribute__((ext_vector_type(8)));

#if __has_builtin(__builtin_amdgcn_exp2f)
#define EXP2(x) __builtin_amdgcn_exp2f(x)
#else
#define EXP2(x) exp2f(x)
#endif

// RNE float -> bf16 bits
__device__ __forceinline__ unsigned short f2bf(float f) {
  unsigned int u = __float_as_uint(f);
  u += 0x7fffu + ((u >> 16) & 1u);
  return (unsigned short)(u >> 16);
}

// pack two floats to bf16 pair, round-half-up
__device__ __forceinline__ unsigned int pk2bf(float f0, float f1) {
  return __builtin_amdgcn_perm(__float_as_uint(f1) + 0x8000u,
                               __float_as_uint(f0) + 0x8000u, 0x07060302u);
}

// pack two floats to bf16 pair, TRUNCATING (1 v_perm) — for P only
__device__ __forceinline__ unsigned int pk2bf_t(float f0, float f1) {
  return __builtin_amdgcn_perm(__float_as_uint(f1), __float_as_uint(f0), 0x07060302u);
}

// async global->LDS, 16 bytes per lane (wave-uniform LDS base + lane*16)
__device__ __forceinline__ void gl_lds16(const short* g, short* lds) {
  __builtin_amdgcn_global_load_lds(
      (const __attribute__((address_space(1))) unsigned int*)g,
      (__attribute__((address_space(3))) unsigned int*)lds, 16, 0, 0);
}

// ---------------- fp32 -> bf16 cast: X + all 4 weights, one dispatch ----------------
__global__ __launch_bounds__(256) void cvt_all(const float4* __restrict__ X,
                                               const float4* __restrict__ Wq,
                                               const float4* __restrict__ Wk,
                                               const float4* __restrict__ Wv,
                                               const float4* __restrict__ Wo,
                                               ushort4* __restrict__ xb,
                                               ushort4* __restrict__ wqkv,
                                               ushort4* __restrict__ wob) {
  const int NX = 8192 * 1024 / 4;
  const int NW = 1024 * 1024 / 4;
  const int NT = NX + 4 * NW;
  int i = blockIdx.x * blockDim.x + threadIdx.x;
  int stride = gridDim.x * blockDim.x;
  for (int idx = i; idx < NT; idx += stride) {
    const float4* s;
    ushort4* d;
    int off;
    if (idx < NX) {
      s = X; d = xb; off = idx;
    } else {
      int j = idx - NX;
      int w = j >> 18;
      off = j & (NW - 1);
      switch (w) {
        case 0: s = Wq; d = wqkv; break;
        case 1: s = Wk; d = wqkv + NW; break;
        case 2: s = Wv; d = wqkv + 2 * NW; break;
        default: s = Wo; d = wob; break;
      }
    }
    float4 f = s[off];
    ushort4 r;
    r.x = f2bf(f.x); r.y = f2bf(f.y); r.z = f2bf(f.z); r.w = f2bf(f.w);
    d[off] = r;
  }
}

// ---------------- GEMM: C[M,N] = A[M,K] * B[N,K]^T (both bf16 row-major) ----------------
// MODE 0: fp32 output to Cf.
// MODE 1: QKV mode, N=3072: cols [0,1024) -> q_o (scaled bf16), [1024,2048) -> k_o,
//         [2048,3072) -> vT_o transposed as (b,h,d,s) with packed 8B stores.
template <int MODE>
__global__ __launch_bounds__(256) void gemm_bt(const short* __restrict__ A,
                                               const short* __restrict__ B,
                                               float* __restrict__ Cf,
                                               short* __restrict__ q_o,
                                               short* __restrict__ k_o,
                                               short* __restrict__ vT_o,
                                               int M, int N, int K) {
  const int tid = threadIdx.x;
  const int wave = tid >> 6, lane = tid & 63;
  const int quad = lane >> 4, l15 = lane & 15;
  const int m0 = blockIdx.x * 128, n0 = blockIdx.y * 128;
  const int wm = (wave >> 1) * 64, wn = (wave & 1) * 64;

  __shared__ __align__(16) short As[128 * 64];
  __shared__ __align__(16) short Bs[128 * 64];

  const f32x4 z4 = {0.f, 0.f, 0.f, 0.f};
  f32x4 acc[4][4];
  for (int i = 0; i < 4; ++i)
    for (int j = 0; j < 4; ++j) acc[i][j] = z4;

  for (int k0 = 0; k0 < K; k0 += 64) {
    __syncthreads();
    for (int i = 0; i < 4; ++i) {
      int c = wave * 4 + i;
      int r = c * 8 + (lane >> 3);
      int c8 = (lane & 7) ^ (r & 7);
      gl_lds16(A + (size_t)(m0 + r) * K + k0 + c8 * 8, As + c * 512 + lane * 8);
      gl_lds16(B + (size_t)(n0 + r) * K + k0 + c8 * 8, Bs + c * 512 + lane * 8);
    }
    __syncthreads();
    for (int kk = 0; kk < 64; kk += 32) {
      int c8b = (kk >> 3) + quad;
      s16x8 af[4], bfr[4];
      for (int mt = 0; mt < 4; ++mt) {
        int row = wm + mt * 16 + l15;
        af[mt] = *(const s16x8*)(As + row * 64 + ((c8b ^ (row & 7)) << 3));
      }
      for (int nt = 0; nt < 4; ++nt) {
        int row = wn + nt * 16 + l15;
        bfr[nt] = *(const s16x8*)(Bs + row * 64 + ((c8b ^ (row & 7)) << 3));
      }
      for (int mt = 0; mt < 4; ++mt)
        for (int nt = 0; nt < 4; ++nt)
          acc[mt][nt] = __builtin_amdgcn_mfma_f32_16x16x32_bf16(af[mt], bfr[nt],
                                                                acc[mt][nt], 0, 0, 0);
    }
  }

  if (MODE == 0) {
    for (int mt = 0; mt < 4; ++mt)
      for (int nt = 0; nt < 4; ++nt) {
        int col = n0 + wn + nt * 16 + l15;
        for (int r = 0; r < 4; ++r) {
          int row = m0 + wm + mt * 16 + quad * 4 + r;
          Cf[(size_t)row * N + col] = acc[mt][nt][r];
        }
      }
  } else {
    if (n0 < 1024) {  // Q, fold softmax scale * log2(e)
      const float scale = 0.18033688011112042f;  // 0.125 * log2(e)
      for (int mt = 0; mt < 4; ++mt)
        for (int nt = 0; nt < 4; ++nt) {
          int col = n0 + wn + nt * 16 + l15;
          for (int r = 0; r < 4; ++r) {
            int row = m0 + wm + mt * 16 + quad * 4 + r;
            ((unsigned short*)q_o)[(size_t)row * 1024 + col] = f2bf(acc[mt][nt][r] * scale);
          }
        }
    } else if (n0 < 2048) {  // K
      for (int mt = 0; mt < 4; ++mt)
        for (int nt = 0; nt < 4; ++nt) {
          int col = n0 - 1024 + wn + nt * 16 + l15;
          for (int r = 0; r < 4; ++r) {
            int row = m0 + wm + mt * 16 + quad * 4 + r;
            ((unsigned short*)k_o)[(size_t)row * 1024 + col] = f2bf(acc[mt][nt][r]);
          }
        }
    } else {  // V transposed: vT[((b*16+h)*64+d)*2048 + s], 4 consecutive s per lane
      for (int mt = 0; mt < 4; ++mt)
        for (int nt = 0; nt < 4; ++nt) {
          int col = n0 - 2048 + wn + nt * 16 + l15;
          int h = col >> 6, d = col & 63;
          int row0 = m0 + wm + mt * 16 + quad * 4;
          int b = row0 >> 11, s = row0 & 2047;
          uint2 pk;
          pk.x = pk2bf(acc[mt][nt][0], acc[mt][nt][1]);
          pk.y = pk2bf(acc[mt][nt][2], acc[mt][nt][3]);
          *(uint2*)((unsigned short*)vT_o + (((size_t)b * 16 + h) * 64 + d) * 2048 + s) = pk;
        }
    }
  }
}

// ---------------- flash attention: 32x32 MFMA, dbuf staging, register-P ----------------
// grid (64 bh, 16 y): qt = 15 - y (heavy blocks dispatch first). 4 waves x 32 q each.
// Lane holds ONE q column (l31) in S^T C-layout -> softmax per-lane, l reduced with a
// single shfl_xor(32). P^T B-frags for PV built from registers; the half-wave
// exchange per 16-kv step is ONE v_permlane32_swap_b32 pair (D.hi <-> S.lo):
//   swap(D=cax, S=cbx):  cax = {ax.lo | bx[lane-32] in hi} = pf.u[0]
//                        cbx = {ax[lane+32] in lo | bx.hi} = pf.u[2]
// replacing 2 selects + 2 shfl_xor(LDS pipe) + 4 selects (exact equivalence).
// K/V^T double-buffered: DMA for t+1 issued right after the single per-iter barrier.
// T5: s_setprio(1) around the QK^T and PV MFMA clusters (R3: −4.3 us total, kept).
__global__ __launch_bounds__(256, 2) void attn_kernel(const short* __restrict__ qb,
                                                      const short* __restrict__ kb,
                                                      const short* __restrict__ vT,
                                                      short* __restrict__ ob) {
  const int bh = blockIdx.x;
  const int qt = 15 - (int)blockIdx.y;
  const int tid = threadIdx.x;
  const int wave = tid >> 6, lane = tid & 63;
  const int l31 = lane & 31, h = lane >> 5;
  const int q0 = qt * 128;
  const size_t rowbase = (size_t)(bh >> 4) * 2048;
  const int hoff = (bh & 15) * 64;

  __shared__ __align__(16) short Ks[2][8192];   // 128 kv x 64 d, swizzled (32 KB)
  __shared__ __align__(16) short VTs[2][8192];  // 64 d x 128 kv, swizzled (32 KB)

  // staging coords: chunks c = wave*4+i, 512 shorts each
  const int kc = wave * 4;
  const int kr = kc * 8 + (lane >> 3);            // K row (8 rows per chunk)
  const short* ksrc = kb + (rowbase + kr) * 1024 + hoff + (((lane & 7) ^ (kr & 7)) << 3);
  const int vg = lane & 15;
  const short* vsrc_i[4];
#pragma unroll
  for (int i = 0; i < 4; ++i) {
    int d = (kc + i) * 4 + (lane >> 4);           // V^T d-row (4 rows per chunk)
    vsrc_i[i] = vT + ((size_t)bh * 64 + d) * 2048 + ((vg ^ (d & 7)) << 3);
  }

  // Q B-frags: lane(q=l31, d = ks*16 + h*8 + j)
  s16x8 qf[4];
  {
    const short* qrow = qb + (rowbase + q0 + wave * 32 + l31) * 1024 + hoff + h * 8;
#pragma unroll
    for (int k = 0; k < 4; ++k) qf[k] = *(const s16x8*)(qrow + k * 16);
  }

  // prologue: stage t=0 into buffer 0
#pragma unroll
  for (int i = 0; i < 4; ++i)
    gl_lds16(ksrc + i * 8 * 1024, Ks[0] + (kc + i) * 512 + lane * 8);
#pragma unroll
  for (int i = 0; i < 4; ++i)
    gl_lds16(vsrc_i[i], VTs[0] + (kc + i) * 512 + lane * 8);

  f32x16 oacc[2];  // O^T: [d-tile], col=q=l31, row_d=(e&3)+8*(e>>2)+4h+32dt
#pragma unroll
  for (int dt = 0; dt < 2; ++dt)
#pragma unroll
    for (int e = 0; e < 16; ++e) oacc[dt][e] = 0.f;
  float lacc = 0.f;
  const int kswz = l31 & 7;

  for (int t = 0; t <= qt; ++t) {
    __syncthreads();  // drains DMA(t) (issued a full iter ago); LDS reads of old buf done
    const int cur = t & 1;

    if (t < qt) {  // stage t+1 into alternate buffers; whole iteration to complete
      const int nxt = cur ^ 1;
      const short* ks = ksrc + (size_t)(t + 1) * 128 * 1024;
#pragma unroll
      for (int i = 0; i < 4; ++i)
        gl_lds16(ks + i * 8 * 1024, Ks[nxt] + (kc + i) * 512 + lane * 8);
#pragma unroll
      for (int i = 0; i < 4; ++i)
        gl_lds16(vsrc_i[i] + (t + 1) * 128, VTs[nxt] + (kc + i) * 512 + lane * 8);
    }

    const short* Kc = Ks[cur];
    const short* Vc = VTs[cur];

    // S^T = K * Q^T, 4 m-tiles of 32 kv, computed in 2 groups to bound registers.
    // C-layout: col=q=l31, row_kv=(e&3)+8*(e>>2)+4h (+32m). Then exp2 + pack to pp.
    unsigned int pp[4][8];  // P bf16 pairs: pp[m][rg] = (reg 2rg, reg 2rg+1)
    float sum = 0.f;
#pragma unroll
    for (int g = 0; g < 2; ++g) {
      f32x16 s0, s1;
#pragma unroll
      for (int e = 0; e < 16; ++e) { s0[e] = 0.f; s1[e] = 0.f; }
      __builtin_amdgcn_s_setprio(1);
#pragma unroll
      for (int ks = 0; ks < 4; ++ks) {
        int pos = ((ks << 1) + h) ^ kswz;
        s16x8 kf0 = *(const s16x8*)(Kc + ((2 * g) * 32 + l31) * 64 + (pos << 3));
        s16x8 kf1 = *(const s16x8*)(Kc + ((2 * g + 1) * 32 + l31) * 64 + (pos << 3));
        s0 = __builtin_amdgcn_mfma_f32_32x32x16_bf16(kf0, qf[ks], s0, 0, 0, 0);
        s1 = __builtin_amdgcn_mfma_f32_32x32x16_bf16(kf1, qf[ks], s1, 0, 0, 0);
      }
      __builtin_amdgcn_s_setprio(0);
      if (t == qt) {  // causal mask on diagonal tile (local compare: t*128 == q0)
        int qg = wave * 32 + l31;
#pragma unroll
        for (int e = 0; e < 16; ++e) {
          int rloc = (e & 3) + 8 * (e >> 2) + 4 * h;
          if ((2 * g) * 32 + rloc > qg) s0[e] = -1e30f;
          if ((2 * g + 1) * 32 + rloc > qg) s1[e] = -1e30f;
        }
      }
#pragma unroll
      for (int rg = 0; rg < 8; ++rg) {
        float a0 = EXP2(s0[2 * rg]), a1 = EXP2(s0[2 * rg + 1]);
        float b0 = EXP2(s1[2 * rg]), b1 = EXP2(s1[2 * rg + 1]);
        sum += (a0 + a1) + (b0 + b1);
        pp[2 * g][rg] = pk2bf_t(a0, a1);
        pp[2 * g + 1][rg] = pk2bf_t(b0, b1);
      }
    }
    lacc += sum;

    // O^T += V^T * P^T. B-frag(kv step s): lane(q=l31, kv=s*16+h*8+j).
    // Half-wave row interleave resolved with one permlane32_swap pair per step.
#pragma unroll
    for (int s = 0; s < 8; ++s) {
      int m = s >> 1, base = (s & 1) * 4;
      unsigned int cax = pp[m][base + 0], cay = pp[m][base + 1];
      unsigned int cbx = pp[m][base + 2], cby = pp[m][base + 3];
      // D.hi <-> S.lo:  cax := {ax.lo, bx.lo(hi-half)}, cbx := {ax.hi(lo-half), bx.hi}
      asm("v_permlane32_swap_b32 %0, %1" : "+v"(cax), "+v"(cbx));
      asm("v_permlane32_swap_b32 %0, %1" : "+v"(cay), "+v"(cby));
      union { s16x8 v; unsigned int u[4]; } pf;
      pf.u[0] = cax;
      pf.u[1] = cay;
      pf.u[2] = cbx;
      pf.u[3] = cby;
      __builtin_amdgcn_s_setprio(1);
#pragma unroll
      for (int dt = 0; dt < 2; ++dt) {
        int d = dt * 32 + l31;
        s16x8 vf = *(const s16x8*)(Vc + d * 128 + ((((s << 1) + h) ^ (d & 7)) << 3));
        oacc[dt] = __builtin_amdgcn_mfma_f32_32x32x16_bf16(vf, pf.v, oacc[dt], 0, 0, 0);
      }
      __builtin_amdgcn_s_setprio(0);
    }
  }

  // epilogue: l across the two half-lanes, normalize, store O rows (8B stores)
  lacc += __shfl_xor(lacc, 32);
  float inv = 1.0f / lacc;
  size_t row = rowbase + q0 + wave * 32 + l31;
  unsigned short* orow = (unsigned short*)ob + row * 1024 + hoff;
#pragma unroll
  for (int dt = 0; dt < 2; ++dt)
#pragma unroll
    for (int rg = 0; rg < 4; ++rg) {
      int d = dt * 32 + rg * 8 + 4 * h;
      uint2 pk;
      pk.x = pk2bf(oacc[dt][rg * 4 + 0] * inv, oacc[dt][rg * 4 + 1] * inv);
      pk.y = pk2bf(oacc[dt][rg * 4 + 2] * inv, oacc[dt][rg * 4 + 3] * inv);
      *(uint2*)(orow + d) = pk;
    }
}

extern "C" void kernel_launch(void* const* d_in, const int* in_sizes, int n_in,
                              void* d_out, int out_size, void* d_ws, size_t ws_size,
                              hipStream_t stream) {
  const float* X  = (const float*)d_in[0];
  const float* Wq = (const float*)d_in[1];
  const float* Wk = (const float*)d_in[2];
  const float* Wv = (const float*)d_in[3];
  const float* Wo = (const float*)d_in[4];

  // workspace (bf16 shorts), 72 MB total; ob aliases xb (dead after QKV gemm)
  short* xb   = (short*)d_ws;                    // 8192x1024 (16 MB)
  short* wqkv = xb + (size_t)8192 * 1024;        // 3072x1024 ( 6 MB)
  short* wob  = wqkv + (size_t)3072 * 1024;      // 1024x1024 ( 2 MB)
  short* qb   = wob + (size_t)1024 * 1024;       // 8192x1024 (16 MB)
  short* kb   = qb + (size_t)8192 * 1024;        // 8192x1024 (16 MB)
  short* vT   = kb + (size_t)8192 * 1024;        // (4,16,64,2048) (16 MB)
  short* ob   = xb;

  const int MB = 8192;

  cvt_all<<<3072, 256, 0, stream>>>((const float4*)X, (const float4*)Wq, (const float4*)Wk,
                                    (const float4*)Wv, (const float4*)Wo, (ushort4*)xb,
                                    (ushort4*)wqkv, (ushort4*)wob);

  // fused QKV projection -> qb (scaled), kb, vT
  gemm_bt<1><<<dim3(64, 24), 256, 0, stream>>>(xb, wqkv, nullptr, qb, kb, vT, MB, 3072, 1024);

  // flash attention -> ob (bf16)
  attn_kernel<<<dim3(64, 16), 256, 0, stream>>>(qb, kb, vT, ob);

  // output projection -> fp32 d_out
  gemm_bt<0><<<dim3(64, 8), 256, 0, stream>>>(ob, wob, (float*)d_out, nullptr, nullptr,
                                              nullptr, MB, 1024, 1024);
}